// Round 6
// baseline (351.313 us; speedup 1.0000x reference)
//
#include <hip/hip_runtime.h>
#include <math.h>

#define B_DIM 16
#define A_DIM 1024
#define V_DIM 512
#define D_DIM 512
#define NEGV  (-1e30f)
#define SKEW_W 768   // 512 data cols + 256 stagger margin, NEG-padded

typedef short bf16x8 __attribute__((ext_vector_type(8)));
typedef float floatx4 __attribute__((ext_vector_type(4)));

// round-to-nearest-even fp32 -> bf16
__device__ __forceinline__ short bf16_rne(float f) {
    unsigned u = __float_as_uint(f);
    return (short)((u + 0x7fffu + ((u >> 16) & 1u)) >> 16);
}

__device__ __forceinline__ float max3f(float a, float b, float c) {
    float d;
    asm("v_max3_f32 %0, %1, %2, %3" : "=v"(d) : "v"(a), "v"(b), "v"(c));
    return d;
}

// ---------------------------------------------------------------------------
// Merged elementwise fp32 -> bf16 for three segments (8 elems/thread).
// ---------------------------------------------------------------------------
__global__ __launch_bounds__(256) void cvt3_bf16_kernel(
    const float* __restrict__ in0, unsigned short* __restrict__ out0, int nb0,
    const float* __restrict__ in1, unsigned short* __restrict__ out1, int nb1,
    const float* __restrict__ in2, unsigned short* __restrict__ out2)
{
    int blk = blockIdx.x;
    const float* in; unsigned short* out;
    if (blk < nb0)              { in = in0; out = out0; }
    else if (blk < nb0 + nb1)   { in = in1; out = out1; blk -= nb0; }
    else                        { in = in2; out = out2; blk -= nb0 + nb1; }
    const int i = blk * 256 + threadIdx.x;
    float4 u = ((const float4*)in)[2*i];
    float4 v = ((const float4*)in)[2*i + 1];
    bf16x8 h;
    h[0]=bf16_rne(u.x); h[1]=bf16_rne(u.y); h[2]=bf16_rne(u.z); h[3]=bf16_rne(u.w);
    h[4]=bf16_rne(v.x); h[5]=bf16_rne(v.y); h[6]=bf16_rne(v.z); h[7]=bf16_rne(v.w);
    *(bf16x8*)(out + (size_t)i * 8) = h;
}

// ---------------------------------------------------------------------------
// bf16 MFMA NT GEMM with register-prefetch K-pipeline. 128x128 tile, BK=32.
// ---------------------------------------------------------------------------
__global__ __launch_bounds__(256) void gemm_bf16_nt(
    const unsigned short* __restrict__ Ag, const unsigned short* __restrict__ Bg,
    const float* __restrict__ bias, float* __restrict__ Cg,
    int M, int N, int K, size_t strA, size_t strB, size_t strC)
{
    __shared__ __align__(16) unsigned short lA[8*64*8];   // 8 KB
    __shared__ __align__(16) unsigned short lB[8*64*8];

    const unsigned short* Ab = Ag + (size_t)blockIdx.z * strA;
    const unsigned short* Bb = Bg + (size_t)blockIdx.z * strB;
    float*                Cb = Cg + (size_t)blockIdx.z * strC;

    const int m0 = blockIdx.y * 128;
    const int n0 = blockIdx.x * 128;
    const int tid = threadIdx.x, lane = tid & 63;
    const int w = tid >> 6, wy = w >> 1, wx = w & 1;

    const int u0 = tid, u1 = tid + 256;
    const int r_u0 = ((u0 >> 6) << 4) + (u0 & 15), k_u0 = ((u0 >> 4) & 3) * 8;
    const int r_u1 = ((u1 >> 6) << 4) + (u1 & 15), k_u1 = ((u1 >> 4) & 3) * 8;

    const unsigned short* gA0 = Ab + (size_t)(m0 + r_u0) * K + k_u0;
    const unsigned short* gA1 = Ab + (size_t)(m0 + r_u1) * K + k_u1;
    const unsigned short* gB0 = Bb + (size_t)(n0 + r_u0) * K + k_u0;
    const unsigned short* gB1 = Bb + (size_t)(n0 + r_u1) * K + k_u1;

    floatx4 acc[4][4];
    #pragma unroll
    for (int i = 0; i < 4; ++i)
        #pragma unroll
        for (int j = 0; j < 4; ++j) acc[i][j] = (floatx4){0.f, 0.f, 0.f, 0.f};

    bf16x8 a0 = *(const bf16x8*)(gA0);
    bf16x8 a1 = *(const bf16x8*)(gA1);
    bf16x8 b0 = *(const bf16x8*)(gB0);
    bf16x8 b1 = *(const bf16x8*)(gB1);

    for (int k0 = 0; k0 < K; k0 += 32) {
        __syncthreads();
        *(bf16x8*)&lA[(size_t)u0 * 8] = a0;
        *(bf16x8*)&lA[(size_t)u1 * 8] = a1;
        *(bf16x8*)&lB[(size_t)u0 * 8] = b0;
        *(bf16x8*)&lB[(size_t)u1 * 8] = b1;
        __syncthreads();

        if (k0 + 32 < K) {
            a0 = *(const bf16x8*)(gA0 + k0 + 32);
            a1 = *(const bf16x8*)(gA1 + k0 + 32);
            b0 = *(const bf16x8*)(gB0 + k0 + 32);
            b1 = *(const bf16x8*)(gB1 + k0 + 32);
        }

        bf16x8 fa[4], fb[4];
        #pragma unroll
        for (int t = 0; t < 4; ++t) {
            fa[t] = *(const bf16x8*)&lA[(((wy*4 + t)*64) + lane) * 8];
            fb[t] = *(const bf16x8*)&lB[(((wx*4 + t)*64) + lane) * 8];
        }
        #pragma unroll
        for (int i = 0; i < 4; ++i)
            #pragma unroll
            for (int j = 0; j < 4; ++j)
                acc[i][j] = __builtin_amdgcn_mfma_f32_16x16x32_bf16(fa[i], fb[j], acc[i][j], 0, 0, 0);
    }

    const int q = lane >> 4, c = lane & 15;
    #pragma unroll
    for (int i = 0; i < 4; ++i)
        #pragma unroll
        for (int j = 0; j < 4; ++j) {
            const int n = n0 + (wx*4 + j)*16 + c;
            const float bv = bias ? bias[n] : 0.f;
            #pragma unroll
            for (int r = 0; r < 4; ++r) {
                const int m = m0 + (wy*4 + i)*16 + q*4 + r;
                Cb[(size_t)m * N + n] = acc[i][j][r] + bv;
            }
        }
}

// ---------------------------------------------------------------------------
// Row L2-normalize fp32 -> bf16. One wave/row (512 cols).
// ---------------------------------------------------------------------------
__global__ __launch_bounds__(256) void rownorm_cvt_kernel(
    const float* __restrict__ in, unsigned short* __restrict__ out)
{
    const int wave = threadIdx.x >> 6;
    const int lane = threadIdx.x & 63;
    const size_t r = (size_t)blockIdx.x * 4 + wave;
    const float* p = in + r * D_DIM + lane * 8;
    float4 u = *(const float4*)p;
    float4 w = *(const float4*)(p + 4);
    float ss = u.x*u.x + u.y*u.y + u.z*u.z + u.w*u.w
             + w.x*w.x + w.y*w.y + w.z*w.z + w.w*w.w;
    #pragma unroll
    for (int m = 1; m < 64; m <<= 1) ss += __shfl_xor(ss, m, 64);
    const float inv = 1.0f / fmaxf(sqrtf(ss), 1e-12f);
    bf16x8 h;
    h[0]=bf16_rne(u.x*inv); h[1]=bf16_rne(u.y*inv); h[2]=bf16_rne(u.z*inv); h[3]=bf16_rne(u.w*inv);
    h[4]=bf16_rne(w.x*inv); h[5]=bf16_rne(w.y*inv); h[6]=bf16_rne(w.z*inv); h[7]=bf16_rne(w.w*inv);
    *(bf16x8*)(out + r * D_DIM + lane * 8) = h;
}

// ---------------------------------------------------------------------------
// DPP helper (wave64). 0x138 = wave_shr:1 (lane l <- l-1; lane 0 keeps oldv
// with bound_ctrl=false). Verified in prior rounds.
// ---------------------------------------------------------------------------
template <int CTRL, int RMASK>
__device__ __forceinline__ float fdpp(float oldv, float src) {
    int r = __builtin_amdgcn_update_dpp(
        __float_as_int(oldv), __float_as_int(src), CTRL, RMASK, 0xF, false);
    return __int_as_float(r);
}

// ---------------------------------------------------------------------------
// Fused: row softmax -> Pbf (bf16) + skewed NEG-padded fp32 copy of the raw
// sim row for the 1-wave staggered DTW.
// DTW row i: lane = i>>4, group q = (i&15)>>2, offset off(i) = 4*lane + q.
// skew row (width 768): data at [off, off+512), NEGV margins elsewhere.
// Margin cols are disjoint from data cols -> no write races in one pass.
// ---------------------------------------------------------------------------
__global__ __launch_bounds__(256) void softmax_skew_kernel(
    const float* __restrict__ sim, unsigned short* __restrict__ Pbf,
    float* __restrict__ skew)
{
    const int wave = threadIdx.x >> 6;
    const int lane = threadIdx.x & 63;
    const size_t r = (size_t)blockIdx.x * 4 + wave;
    const float* p = sim + r * V_DIM + lane * 8;
    float4 u = *(const float4*)p;
    float4 w = *(const float4*)(p + 4);
    float s[8] = {u.x,u.y,u.z,u.w,w.x,w.y,w.z,w.w};

    float m = s[0];
    #pragma unroll
    for (int k = 1; k < 8; ++k) m = fmaxf(m, s[k]);
    #pragma unroll
    for (int t = 1; t < 64; t <<= 1) m = fmaxf(m, __shfl_xor(m, t, 64));

    const float L2E = 1.44269504f;
    float ex[8];
    float e = 0.f;
    #pragma unroll
    for (int k = 0; k < 8; ++k) { ex[k] = exp2f((s[k] - m) * L2E); e += ex[k]; }
    #pragma unroll
    for (int t = 1; t < 64; t <<= 1) e += __shfl_xor(e, t, 64);
    const float ri = 1.0f / e;

    bf16x8 h;
    #pragma unroll
    for (int k = 0; k < 8; ++k) h[k] = bf16_rne(ex[k] * ri);
    *(bf16x8*)(Pbf + r * V_DIM + lane * 8) = h;

    // skewed NEG-padded copy
    const int i  = (int)r & 1023;
    const int sh = 4 * (i >> 4) + ((i & 15) >> 2);   // = off(i), 0..255
    float* Sk = skew + (size_t)r * SKEW_W;
    #pragma unroll
    for (int k = 0; k < 8; ++k) Sk[sh + lane * 8 + k] = s[k];
    #pragma unroll
    for (int k2 = 0; k2 < 4; ++k2) {                 // 256 margin cols / 64 lanes
        int col = sh + 512 + lane * 4 + k2;
        if (col >= SKEW_W) col -= SKEW_W;
        Sk[col] = NEGV;
    }
}

// ---------------------------------------------------------------------------
// Batched 32x32 transpose + cvt: video[b][v][d] fp32 -> vT[b][d][v] bf16.
// ---------------------------------------------------------------------------
__global__ __launch_bounds__(256) void transpose_cvt_kernel(
    const float* __restrict__ in, unsigned short* __restrict__ out)
{
    __shared__ float t[32][33];
    const int b = blockIdx.z;
    const int v0 = blockIdx.y * 32, d0 = blockIdx.x * 32;
    const int x = threadIdx.x & 31, y0 = (threadIdx.x >> 5) * 4;
    const float* I = in + ((size_t)b * V_DIM + v0) * D_DIM + d0;
    #pragma unroll
    for (int r = 0; r < 4; ++r) t[y0 + r][x] = I[(size_t)(y0 + r) * D_DIM + x];
    __syncthreads();
    unsigned short* O = out + ((size_t)b * D_DIM + d0) * V_DIM + v0;
    #pragma unroll
    for (int r = 0; r < 4; ++r) O[(size_t)(y0 + r) * V_DIM + x] = (unsigned short)bf16_rne(t[x][y0 + r]);
}

// ---------------------------------------------------------------------------
// Fused PV GEMM + 1-WAVE staggered DTW (no barriers, no LDS in DTW).
// DTW (blocks 0..15, one wave): lane owns rows 16*lane..16*lane+15 as 4
// groups of 4 rows; group q staggered 1 col behind group q-1 (off=4*lane+q).
// Groups are independent within a step (up/diag from prev-step registers);
// each group is a serial 4-cell chain (R5-verified cell math). Lane->lane
// handoff = 1 intra-wave DPP/step. Out-of-window cells read NEGV padding and
// compute bounded garbage (>= -8e32) that max3 discards -> no predication.
// ---------------------------------------------------------------------------
__global__ __launch_bounds__(256) void pv_dtw_kernel(
    const unsigned short* __restrict__ Pbf, const unsigned short* __restrict__ vTb,
    const float* __restrict__ skew, float* __restrict__ out_aligned,
    float* __restrict__ out_score)
{
    __shared__ __align__(16) unsigned short lA[8*64*8];
    __shared__ __align__(16) unsigned short lB[8*64*8];

    if (blockIdx.x < 16) {
        // ---------------- DTW path (one wave) ----------------
        if (threadIdx.x >= 64) return;
        const int b    = blockIdx.x;
        const int lane = threadIdx.x;
        const float* base = skew + (size_t)b * 1024 * SKEW_W;

        int voA[16], voB[16];
        #pragma unroll
        for (int j = 0; j < 16; ++j) {
            voA[j] = (lane * 16 + j) * SKEW_W;
            voB[j] = voA[j] + 4;
        }
        float4 A[16], B[16];
        #pragma unroll
        for (int j = 0; j < 16; ++j) A[j] = *(const float4*)(base + voA[j]);
        #pragma unroll
        for (int j = 0; j < 16; ++j) B[j] = *(const float4*)(base + voB[j]);

        float dp00=NEGV, dp01=NEGV, dp02=NEGV, dp03=NEGV;
        float dp10=NEGV, dp11=NEGV, dp12=NEGV, dp13=NEGV;
        float dp20=NEGV, dp21=NEGV, dp22=NEGV, dp23=NEGV;
        float dp30=NEGV, dp31=NEGV, dp32=NEGV, dp33=NEGV;
        float uc0=NEGV, uc1=NEGV, uc2=NEGV, uc3=NEGV;
        float uo1=NEGV, uo2=NEGV, uo3=NEGV;
        float uo0 = (lane == 0) ? 0.0f : NEGV;   // diag for cell (0,0)

// serial cell: u=up(new neighbor above, same col), g=diag; updates u,g chain
#define CELL(CVAL, DP) { float o_ = DP; float n_ = (CVAL) + max3f(u, DP, g); DP = n_; g = o_; u = n_; }

#define DTW_STEP(BUF, COMP, TT)                                               \
        {                                                                     \
            float u, g, n1, n2, n3;                                           \
            u = uc0; g = uo0;                                                 \
            CELL(BUF[0].COMP,  dp00) CELL(BUF[1].COMP,  dp01)                 \
            CELL(BUF[2].COMP,  dp02) CELL(BUF[3].COMP,  dp03)                 \
            n1 = dp03;                                                        \
            u = uc1; g = uo1;                                                 \
            CELL(BUF[4].COMP,  dp10) CELL(BUF[5].COMP,  dp11)                 \
            CELL(BUF[6].COMP,  dp12) CELL(BUF[7].COMP,  dp13)                 \
            n2 = dp13;                                                        \
            u = uc2; g = uo2;                                                 \
            CELL(BUF[8].COMP,  dp20) CELL(BUF[9].COMP,  dp21)                 \
            CELL(BUF[10].COMP, dp22) CELL(BUF[11].COMP, dp23)                 \
            n3 = dp23;                                                        \
            u = uc3; g = uo3;                                                 \
            CELL(BUF[12].COMP, dp30) CELL(BUF[13].COMP, dp31)                 \
            CELL(BUF[14].COMP, dp32) CELL(BUF[15].COMP, dp33)                 \
            if ((TT) == 766 && lane == 63) out_score[b] = dp33;               \
            uo0 = uc0; uc0 = fdpp<0x138, 0xF>(NEGV, dp33);                    \
            uo1 = uc1; uc1 = n1;                                              \
            uo2 = uc2; uc2 = n2;                                              \
            uo3 = uc3; uc3 = n3;                                              \
        }

        #pragma unroll 1
        for (int t4 = 0; t4 < 768; t4 += 8) {
            DTW_STEP(A, x, t4+0) DTW_STEP(A, y, t4+1)
            DTW_STEP(A, z, t4+2) DTW_STEP(A, w, t4+3)
            if (t4 + 8 <= 764) {
                #pragma unroll
                for (int j = 0; j < 16; ++j) { voA[j] += 8; A[j] = *(const float4*)(base + voA[j]); }
            }
            DTW_STEP(B, x, t4+4) DTW_STEP(B, y, t4+5)
            DTW_STEP(B, z, t4+6) DTW_STEP(B, w, t4+7)
            if (t4 + 12 <= 764) {
                #pragma unroll
                for (int j = 0; j < 16; ++j) { voB[j] += 8; B[j] = *(const float4*)(base + voB[j]); }
            }
        }
#undef DTW_STEP
#undef CELL
        return;
    }

    // ---------------- PV GEMM path ----------------
    const int bid = blockIdx.x - 16;
    const int n0 = (bid & 3) * 128;          // D/128 = 4
    const int m0 = ((bid >> 2) & 7) * 128;   // A/128 = 8
    const int bz = bid >> 5;                 // 16 batches
    const int K = V_DIM, N = D_DIM;

    const unsigned short* Ab = Pbf + (size_t)bz * A_DIM * V_DIM;
    const unsigned short* Bb = vTb + (size_t)bz * V_DIM * D_DIM;
    float*                Cb = out_aligned + (size_t)bz * A_DIM * D_DIM;

    const int tid = threadIdx.x, lane = tid & 63;
    const int w = tid >> 6, wy = w >> 1, wx = w & 1;
    const int u0 = tid, u1 = tid + 256;
    const int r_u0 = ((u0 >> 6) << 4) + (u0 & 15), k_u0 = ((u0 >> 4) & 3) * 8;
    const int r_u1 = ((u1 >> 6) << 4) + (u1 & 15), k_u1 = ((u1 >> 4) & 3) * 8;

    const unsigned short* gA0 = Ab + (size_t)(m0 + r_u0) * K + k_u0;
    const unsigned short* gA1 = Ab + (size_t)(m0 + r_u1) * K + k_u1;
    const unsigned short* gB0 = Bb + (size_t)(n0 + r_u0) * K + k_u0;
    const unsigned short* gB1 = Bb + (size_t)(n0 + r_u1) * K + k_u1;

    floatx4 acc[4][4];
    #pragma unroll
    for (int i = 0; i < 4; ++i)
        #pragma unroll
        for (int j = 0; j < 4; ++j) acc[i][j] = (floatx4){0.f, 0.f, 0.f, 0.f};

    bf16x8 a0 = *(const bf16x8*)(gA0);
    bf16x8 a1 = *(const bf16x8*)(gA1);
    bf16x8 b0 = *(const bf16x8*)(gB0);
    bf16x8 b1 = *(const bf16x8*)(gB1);

    for (int k0 = 0; k0 < K; k0 += 32) {
        __syncthreads();
        *(bf16x8*)&lA[(size_t)u0 * 8] = a0;
        *(bf16x8*)&lA[(size_t)u1 * 8] = a1;
        *(bf16x8*)&lB[(size_t)u0 * 8] = b0;
        *(bf16x8*)&lB[(size_t)u1 * 8] = b1;
        __syncthreads();
        if (k0 + 32 < K) {
            a0 = *(const bf16x8*)(gA0 + k0 + 32);
            a1 = *(const bf16x8*)(gA1 + k0 + 32);
            b0 = *(const bf16x8*)(gB0 + k0 + 32);
            b1 = *(const bf16x8*)(gB1 + k0 + 32);
        }
        bf16x8 fa[4], fb[4];
        #pragma unroll
        for (int t = 0; t < 4; ++t) {
            fa[t] = *(const bf16x8*)&lA[(((wy*4 + t)*64) + lane) * 8];
            fb[t] = *(const bf16x8*)&lB[(((wx*4 + t)*64) + lane) * 8];
        }
        #pragma unroll
        for (int i = 0; i < 4; ++i)
            #pragma unroll
            for (int j = 0; j < 4; ++j)
                acc[i][j] = __builtin_amdgcn_mfma_f32_16x16x32_bf16(fa[i], fb[j], acc[i][j], 0, 0, 0);
    }

    const int q = lane >> 4, c = lane & 15;
    #pragma unroll
    for (int i = 0; i < 4; ++i)
        #pragma unroll
        for (int j = 0; j < 4; ++j) {
            const int n = n0 + (wx*4 + j)*16 + c;
            #pragma unroll
            for (int r = 0; r < 4; ++r) {
                const int m = m0 + (wy*4 + i)*16 + q*4 + r;
                Cb[(size_t)m * N + n] = acc[i][j][r];
            }
        }
}

// ---------------------------------------------------------------------------
extern "C" void kernel_launch(void* const* d_in, const int* in_sizes, int n_in,
                              void* d_out, int out_size, void* d_ws, size_t ws_size,
                              hipStream_t stream)
{
    const float* audio = (const float*)d_in[0];   // [16,1024,512]
    const float* video = (const float*)d_in[1];   // [16, 512,512]
    const float* W     = (const float*)d_in[2];   // [512,512]
    const float* bias  = (const float*)d_in[3];   // [512]

    float* out_aligned = (float*)d_out;
    float* out_score   = (float*)d_out + (size_t)B_DIM * A_DIM * D_DIM;

    const size_t NA = (size_t)B_DIM * A_DIM * D_DIM;   // 8.39M
    const size_t NV = (size_t)B_DIM * V_DIM * D_DIM;   // 4.19M
    const size_t NS = (size_t)B_DIM * A_DIM * V_DIM;   // 8.39M

    float* ws = (float*)d_ws;
    float*          a_p  = ws;                                 // NA fp32 [dead after rownorm-a]
    float*          v_p  = a_p + NA;                           // NV fp32
    float*          sim  = v_p + NV;                           // NS fp32
    unsigned short* abf  = (unsigned short*)(sim + NS);        // NA bf16 [dead after proj-a]
    unsigned short* vbf  = (unsigned short*)(sim + NS) + NA;   // NV bf16 [dead after proj-v]
    unsigned short* v_nb = vbf + NV;                           // NV bf16
    unsigned short* Wbf  = v_nb + NV;                          // 262144 bf16
    unsigned short* a_nb = (unsigned short*)v_p;               // NA bf16 reuses v_p
    unsigned short* Pbf  = abf;                                // NS bf16 reuses dead abf
    unsigned short* vTb  = vbf;                                // NV bf16 reuses dead vbf
    // skew: 16*1024*768 fp32 = 12.58M floats — exactly overlays a_p (8.39M) +
    // v_p (4.19M), both dead when softmax_skew (disp 7) writes it.
    float*          skew = a_p;

    // 1) fp32 -> bf16 input conversions, one merged launch
    {
        const int nb_a = (int)(NA / 8 / 256);             // 4096
        const int nb_v = (int)(NV / 8 / 256);             // 2048
        const int nb_w = D_DIM * D_DIM / 8 / 256;         // 128
        cvt3_bf16_kernel<<<dim3(nb_a + nb_v + nb_w), dim3(256), 0, stream>>>(
            audio, abf, nb_a, video, vbf, nb_v, W, Wbf);
    }

    // 2) projections: X @ W^T + b
    gemm_bf16_nt<<<dim3(D_DIM/128, (B_DIM*A_DIM)/128, 1), dim3(256), 0, stream>>>(
        abf, Wbf, bias, a_p, B_DIM*A_DIM, D_DIM, D_DIM, 0, 0, 0);
    gemm_bf16_nt<<<dim3(D_DIM/128, (B_DIM*V_DIM)/128, 1), dim3(256), 0, stream>>>(
        vbf, Wbf, bias, v_p, B_DIM*V_DIM, D_DIM, D_DIM, 0, 0, 0);

    // 3) normalize -> bf16 (v first: frees v_p for a_nb)
    rownorm_cvt_kernel<<<dim3((B_DIM*V_DIM)/4), dim3(256), 0, stream>>>(v_p, v_nb);
    rownorm_cvt_kernel<<<dim3((B_DIM*A_DIM)/4), dim3(256), 0, stream>>>(a_p, a_nb);

    // 4) sim[b] = a_n[b] @ v_n[b]^T
    gemm_bf16_nt<<<dim3(V_DIM/128, A_DIM/128, B_DIM), dim3(256), 0, stream>>>(
        a_nb, v_nb, nullptr, sim, A_DIM, V_DIM, D_DIM,
        (size_t)A_DIM*D_DIM, (size_t)V_DIM*D_DIM, (size_t)A_DIM*V_DIM);

    // 5) video -> vT bf16 (independent of sim)
    transpose_cvt_kernel<<<dim3(D_DIM/32, V_DIM/32, B_DIM), dim3(256), 0, stream>>>(video, vTb);

    // 6) fused row softmax -> Pbf + skewed NEG-padded sim copy for DTW
    softmax_skew_kernel<<<dim3((B_DIM*A_DIM)/4), dim3(256), 0, stream>>>(sim, Pbf, skew);

    // 7) fused PV GEMM + 1-wave staggered DTW
    pv_dtw_kernel<<<dim3(16 + (D_DIM/128)*(A_DIM/128)*B_DIM), dim3(256), 0, stream>>>(
        Pbf, vTb, skew, out_aligned, out_score);
}